// Round 2
// baseline (279.834 us; speedup 1.0000x reference)
//
#include <hip/hip_runtime.h>
#include <math.h>

#define NTOK 32768          // B*L
#define DDIM 1024
#define HDIM 64
#define NB 16
#define LN_EPS 1e-5f

#define IDX_OFF  ((size_t)NTOK * NB)                 // 524288
#define AUX_OFF  (IDX_OFF + (size_t)NTOK * 2)        // 589824
#define WT_OFF   (AUX_OFF + 1)                       // 589825

// ws float layout:
//   [0, 1024)              csg partials  (16 d-blocks x 64 cols)
//   [1024, 2048)           csb partials
//   [2048 + blk*32, +32)   per-block partials: [0:16) counts, [16:32) Psum
#define WS_BLK 2048

__global__ void colsum_kernel(const float* __restrict__ W1,
                              const float* __restrict__ gamma,
                              const float* __restrict__ beta,
                              float* __restrict__ ws) {
    __shared__ float sg[4][64];
    __shared__ float sb[4][64];
    const int t = threadIdx.x;          // 256
    const int j = t & 63;
    const int part = t >> 6;            // 0..3
    const int d0 = blockIdx.x * 64 + part * 16;
    float ag = 0.f, ab = 0.f;
    for (int dd = 0; dd < 16; ++dd) {
        const int d = d0 + dd;
        const float w = W1[d * HDIM + j];
        ag += gamma[d] * w;
        ab += beta[d] * w;
    }
    sg[part][j] = ag;
    sb[part][j] = ab;
    __syncthreads();
    if (t < 64) {
        ws[blockIdx.x * 64 + t]        = sg[0][t] + sg[1][t] + sg[2][t] + sg[3][t];
        ws[1024 + blockIdx.x * 64 + t] = sb[0][t] + sb[1][t] + sb[2][t] + sb[3][t];
    }
}

__global__ __launch_bounds__(256, 2)
void router_main(const float* __restrict__ x,
                 const float* __restrict__ gamma,
                 const float* __restrict__ W1,
                 const float* __restrict__ W2,
                 const float* __restrict__ cs,      // = ws (csg/csb partials, read-only)
                 float* __restrict__ blkpart,       // = ws + WS_BLK (write-only region)
                 float* __restrict__ out) {
    __shared__ __align__(16) float Asub[32][64];    // [k][token], stride-1 reads
    __shared__ float plds[4][64][17];               // per-wave logit partials (pad 17)
    __shared__ float s1l[64], s2l[64];
    __shared__ float cps[32];                       // [0:16) counts (LDS atomics)

    const int t    = threadIdx.x;
    const int lane = t & 63;                        // token within tile (hot loop)
    const int wv   = t >> 6;                        // wave 0..3
    const int tok0 = blockIdx.x * 64;

    // staging role: token row r, k-quad kq (coalesced 64B-per-row loads)
    const int r  = t >> 2;                          // 0..63
    const int kq = t & 3;                           // 0..3

    // wave-uniform column base -> W1/W2/cs reads become s_load
    const int jw = __builtin_amdgcn_readfirstlane(wv * 16);

    float acc[16];
#pragma unroll
    for (int c = 0; c < 16; ++c) acc[c] = 0.f;
    float s1p = 0.f, s2p = 0.f;

    const float* xrow = x + (size_t)(tok0 + r) * DDIM;

    // prefetch chunk 0
    float4 xa = *(const float4*)(xrow + kq * 4);
    float4 xb = *(const float4*)(xrow + 16 + kq * 4);
    float4 ga = *(const float4*)(gamma + kq * 4);
    float4 gb = *(const float4*)(gamma + 16 + kq * 4);

    if (t < 32) cps[t] = 0.f;

    for (int kc = 0; kc < 32; ++kc) {
        const int k0 = kc * 32;

        // LN stats on raw x (this thread's fixed k-columns across all chunks)
        s1p += xa.x + xa.y + xa.z + xa.w + xb.x + xb.y + xb.z + xb.w;
        s2p += xa.x * xa.x + xa.y * xa.y + xa.z * xa.z + xa.w * xa.w
             + xb.x * xb.x + xb.y * xb.y + xb.z * xb.z + xb.w * xb.w;

        __syncthreads();                 // previous compute done reading Asub

        Asub[kq * 4 + 0][r] = xa.x * ga.x;
        Asub[kq * 4 + 1][r] = xa.y * ga.y;
        Asub[kq * 4 + 2][r] = xa.z * ga.z;
        Asub[kq * 4 + 3][r] = xa.w * ga.w;
        Asub[16 + kq * 4 + 0][r] = xb.x * gb.x;
        Asub[16 + kq * 4 + 1][r] = xb.y * gb.y;
        Asub[16 + kq * 4 + 2][r] = xb.z * gb.z;
        Asub[16 + kq * 4 + 3][r] = xb.w * gb.w;

        // prefetch next chunk into registers (in flight across compute)
        const int kn = (kc < 31) ? (k0 + 32) : 0;
        float4 nxa = *(const float4*)(xrow + kn + kq * 4);
        float4 nxb = *(const float4*)(xrow + kn + 16 + kq * 4);
        float4 nga = *(const float4*)(gamma + kn + kq * 4);
        float4 ngb = *(const float4*)(gamma + kn + 16 + kq * 4);

        __syncthreads();                 // Asub ready

        const float* w1p = W1 + (size_t)k0 * HDIM + jw;   // uniform -> s_load
#pragma unroll
        for (int kk = 0; kk < 32; ++kk) {
            const float a = Asub[kk][lane];               // stride-1, conflict-free
#pragma unroll
            for (int c = 0; c < 16; ++c)
                acc[c] = fmaf(a, w1p[kk * HDIM + c], acc[c]);
        }

        xa = nxa; xb = nxb; ga = nga; gb = ngb;
    }

    // reduce LN stats over the 4 lanes sharing token r (same wave)
    s1p += __shfl_xor(s1p, 1, 64);
    s1p += __shfl_xor(s1p, 2, 64);
    s2p += __shfl_xor(s2p, 1, 64);
    s2p += __shfl_xor(s2p, 2, 64);
    if ((t & 3) == 0) { s1l[r] = s1p; s2l[r] = s2p; }
    __syncthreads();

    // ---- epilogue: token = lane, cols jw..jw+15 ----
    const float mu   = s1l[lane] * (1.0f / 1024.0f);
    const float var  = s2l[lane] * (1.0f / 1024.0f) - mu * mu;
    const float rstd = 1.0f / sqrtf(var + LN_EPS);

    // colsum(gamma*W1), colsum(beta*W1) for this wave's cols (uniform s_loads)
    float csg[16], csb[16];
#pragma unroll
    for (int c = 0; c < 16; ++c) { csg[c] = 0.f; csb[c] = 0.f; }
    for (int b = 0; b < 16; ++b) {
#pragma unroll
        for (int c = 0; c < 16; ++c) {
            csg[c] += cs[b * 64 + jw + c];
            csb[c] += cs[1024 + b * 64 + jw + c];
        }
    }

    // LN-fold + exact GELU, h stays in registers
#pragma unroll
    for (int c = 0; c < 16; ++c) {
        const float pre = rstd * (acc[c] - mu * csg[c]) + csb[c];
        acc[c] = 0.5f * pre * (1.0f + erff(pre * 0.70710678118654752f));
    }

    // partial logits: lp[nb] = sum_c h[c] * W2[jw+c][nb]  (W2 rows via s_load)
    float lp[16];
#pragma unroll
    for (int nb = 0; nb < NB; ++nb) lp[nb] = 0.f;
    for (int c = 0; c < 16; ++c) {
        const float h = acc[c];
        const float* w2r = W2 + (size_t)(jw + c) * NB;    // uniform -> s_load
#pragma unroll
        for (int nb = 0; nb < NB; ++nb) lp[nb] = fmaf(h, w2r[nb], lp[nb]);
    }
#pragma unroll
    for (int nb = 0; nb < NB; ++nb) plds[wv][lane][nb] = lp[nb] * 0.5f;  // /TEMP
    __syncthreads();

    // ---- softmax + top-2 (one thread per token) ----
    if (t < 64) {
        float p[16];
        float mx = -1e30f;
#pragma unroll
        for (int i = 0; i < NB; ++i) {
            p[i] = plds[0][t][i] + plds[1][t][i] + plds[2][t][i] + plds[3][t][i];
            mx = fmaxf(mx, p[i]);
        }
        float s = 0.f;
#pragma unroll
        for (int i = 0; i < NB; ++i) { p[i] = expf(p[i] - mx); s += p[i]; }
        const float inv = 1.0f / s;
#pragma unroll
        for (int i = 0; i < NB; ++i) p[i] *= inv;

        // probs out + stash for Psum reduction
        float* po = out + (size_t)(tok0 + t) * NB;
#pragma unroll
        for (int i = 0; i < NB; ++i) { po[i] = p[i]; plds[0][t][i] = p[i]; }

        // top-2 (strict >, ties keep lower index — matches lax.top_k)
        float b0 = -1.f, b1 = -1.f;
        int i0 = 0, i1 = 0;
#pragma unroll
        for (int i = 0; i < NB; ++i) {
            if (p[i] > b0)      { b1 = b0; i1 = i0; b0 = p[i]; i0 = i; }
            else if (p[i] > b1) { b1 = p[i]; i1 = i; }
        }
        const float wsum = b0 + b1 + 1e-8f;
        out[IDX_OFF + (size_t)(tok0 + t) * 2]     = (float)i0;
        out[IDX_OFF + (size_t)(tok0 + t) * 2 + 1] = (float)i1;
        out[WT_OFF + (size_t)(tok0 + t) * 2]      = b0 / wsum;
        out[WT_OFF + (size_t)(tok0 + t) * 2 + 1]  = b1 / wsum;
        atomicAdd(&cps[i0], 1.0f);
        atomicAdd(&cps[i1], 1.0f);
    }
    __syncthreads();

    // per-block partials for aux loss (no global atomics, no memset needed)
    if (t < 16) {
        float ps = 0.f;
        for (int m = 0; m < 64; ++m) ps += plds[0][m][t];
        blkpart[(size_t)blockIdx.x * 32 + 16 + t] = ps;     // Psum partial
        blkpart[(size_t)blockIdx.x * 32 + t]      = cps[t]; // counts partial
    }
}

__global__ void aux_kernel(const float* __restrict__ ws, float* __restrict__ out) {
    __shared__ float red[8][32];
    const int t = threadIdx.x;          // 256
    const int i = t & 31;
    const int part = t >> 5;            // 0..7
    float s = 0.f;
    for (int b = part; b < 512; b += 8) s += ws[WS_BLK + (size_t)b * 32 + i];
    red[part][i] = s;
    __syncthreads();
    if (t < 32) {
        float tot = 0.f;
#pragma unroll
        for (int pp = 0; pp < 8; ++pp) tot += red[pp][t];
        red[0][t] = tot;
    }
    __syncthreads();
    if (t == 0) {
        float a = 0.f;
        for (int i2 = 0; i2 < 16; ++i2) {
            const float f = red[0][i2] / (65536.0f + 1e-8f);      // counts / (B*L*K)
            const float P = red[0][16 + i2] * (1.0f / 32768.0f);  // mean prob
            a += f * P;
        }
        out[AUX_OFF] = 16.0f * a;                                 // NB * sum(f*P)
    }
}

extern "C" void kernel_launch(void* const* d_in, const int* in_sizes, int n_in,
                              void* d_out, int out_size, void* d_ws, size_t ws_size,
                              hipStream_t stream) {
    const float* x     = (const float*)d_in[0];
    const float* gamma = (const float*)d_in[1];
    const float* beta  = (const float*)d_in[2];
    const float* W1    = (const float*)d_in[3];
    const float* W2    = (const float*)d_in[4];
    float* out = (float*)d_out;
    float* ws  = (float*)d_ws;

    colsum_kernel<<<16, 256, 0, stream>>>(W1, gamma, beta, ws);
    router_main<<<NTOK / 64, 256, 0, stream>>>(x, gamma, W1, W2,
                                               ws, ws + WS_BLK, out);
    aux_kernel<<<1, 256, 0, stream>>>(ws, out);
}